// Round 14
// baseline (23.557 us; speedup 1.0000x reference)
//
#include <hip/hip_runtime.h>

#define NS 8192
#define MS 2048
#define DD 32
#define MSPLIT 32
#define MCH 64
#define NITS 4

typedef __attribute__((ext_vector_type(8))) short bf16x8;
typedef __attribute__((ext_vector_type(4))) float f32x4;
typedef unsigned short u16;
typedef unsigned int u32;

// ws byte offsets.
// W arrays in fragment-tile order: idx_u16(m,g,j) = ((m>>4)*4+g)*128 + (m&15)*8 + j
//   -> block mb's slice is [mb*2048, mb*2048+2048) u16, contiguous.
#define WBH_OFF  0                          // B hi, M*32 u16 = 128 KB
#define WBL_OFF  (WBH_OFF + MS*32*2)
#define WCH_OFF  (WBL_OFF + MS*32*2)
#define WCL_OFF  (WCH_OFF + MS*32*2)
#define XH_OFF   (WCL_OFF + MS*32*2)        // [N][32] u16 = 512 KB each
#define XL_OFF   (XH_OFF + NS*DD*2)
#define QH_OFF   (XL_OFF + NS*DD*2)
#define QL_OFF   (QH_OFF + NS*DD*2)
#define A2_OFF   (QL_OFF + NS*DD*2)         // [M] f32
#define PART_OFF (A2_OFF + MS*4)            // [MSPLIT][NS] f32
#define DIST_OFF (PART_OFF + MSPLIT*NS*4)   // [NS] f32
#define MM_OFF   (DIST_OFF + NS*4)          // 2 u32

__device__ inline float fast_exp2(float x) {
#if __has_builtin(__builtin_amdgcn_exp2f)
    return __builtin_amdgcn_exp2f(x);
#else
    return exp2f(x);
#endif
}

__device__ inline u32 cvt_pk_bf16(float a, float b) {
    u32 r;
    asm("v_cvt_pk_bf16_f32 %0, %1, %2" : "=v"(r) : "v"(a), "v"(b));
    return r;
}

// Split 8 floats into hi/lo bf16x8 (RNE). Pack-order safe: X and W use the
// same helper, so MFMA dots pair identical k-elements either way.
__device__ inline void split8(const float* v, bf16x8& hi, bf16x8& lo) {
    union { u32 u[4]; bf16x8 b; } H, L;
#pragma unroll
    for (int j = 0; j < 4; ++j) {
        u32 h = cvt_pk_bf16(v[2 * j], v[2 * j + 1]);
        float ha = __uint_as_float(h << 16);
        float hb = __uint_as_float(h & 0xFFFF0000u);
        L.u[j] = cvt_pk_bf16(v[2 * j] - ha, v[2 * j + 1] - hb);
        H.u[j] = h;
    }
    hi = H.b;
    lo = L.b;
}

// One-shot conversion (removes the 32x redundant per-block conversion that made
// kde_fused VALU-bound: 510 inst/thread -> ~210).
// blocks 0..63: W path, one thread per (m, 8-d chunk); blocks 64..319: X path.
__global__ __launch_bounds__(256) void prep(const float* __restrict__ samples,
                                            const float* __restrict__ means,
                                            const float* __restrict__ stds,
                                            unsigned char* __restrict__ ws) {
    const int tid = threadIdx.x, bid = blockIdx.x;
    if (bid == 0 && tid == 0) {
        unsigned* mm = (unsigned*)(ws + MM_OFF);
        mm[0] = 0x7f7fffffu;  // FLT_MAX bits
        mm[1] = 0u;
    }
    const float L2E = 1.4426950408889634f;
    if (bid < 64) {
        const int p = bid * 256 + tid;   // < 16384
        const int m = p >> 3;
        const int c = p & 7;             // c<4: B rows (g=c), c>=4: C rows (g=c-4)
        const int g = c & 3;
        const bool isB = (c < 4);

        const float* mp = means + (size_t)m * DD + g * 8;
        const float* vp = stds  + (size_t)m * DD + g * 8;
        float4 a4 = *(const float4*)mp, b4 = *(const float4*)(mp + 4);
        float4 c4 = *(const float4*)vp, d4 = *(const float4*)(vp + 4);
        float mu[8] = {a4.x, a4.y, a4.z, a4.w, b4.x, b4.y, b4.z, b4.w};
        float sd[8] = {c4.x, c4.y, c4.z, c4.w, d4.x, d4.y, d4.z, d4.w};
        float val[8], a = 0.f;
#pragma unroll
        for (int j = 0; j < 8; ++j) {
            float inv = 1.0f / sd[j];
            val[j] = isB ? (L2E * mu[j] * inv) : (-0.5f * L2E * inv);
            if (isB) a += mu[j] * mu[j] * inv;
        }
        a += __shfl_xor(a, 1);
        a += __shfl_xor(a, 2);
        a += __shfl_xor(a, 4);
        if (c == 0) ((float*)(ws + A2_OFF))[m] = -0.5f * L2E * a - 11.0f; // -log2(M)

        bf16x8 hi, lo;
        split8(val, hi, lo);
        const size_t idx = (size_t)((m >> 4) * 4 + g) * 128 + (m & 15) * 8;
        u16* WH = (u16*)(ws + (isB ? WBH_OFF : WCH_OFF));
        u16* WL = (u16*)(ws + (isB ? WBL_OFF : WCL_OFF));
        *(bf16x8*)(WH + idx) = hi;
        *(bf16x8*)(WL + idx) = lo;
    } else {
        const int idx = (bid - 64) * 256 + tid;  // < NS*DD/4
        float4 v = ((const float4*)samples)[idx];
        float xv[4] = {v.x, v.y, v.z, v.w};
        float qv[4];
#pragma unroll
        for (int j = 0; j < 4; ++j) qv[j] = xv[j] * xv[j];
        union { u32 u[2]; ushort4 s; } HX, LX, HQ, LQ;
#pragma unroll
        for (int j = 0; j < 2; ++j) {
            u32 h = cvt_pk_bf16(xv[2 * j], xv[2 * j + 1]);
            float ha = __uint_as_float(h << 16);
            float hb = __uint_as_float(h & 0xFFFF0000u);
            LX.u[j] = cvt_pk_bf16(xv[2 * j] - ha, xv[2 * j + 1] - hb);
            HX.u[j] = h;
            h = cvt_pk_bf16(qv[2 * j], qv[2 * j + 1]);
            ha = __uint_as_float(h << 16);
            hb = __uint_as_float(h & 0xFFFF0000u);
            LQ.u[j] = cvt_pk_bf16(qv[2 * j] - ha, qv[2 * j + 1] - hb);
            HQ.u[j] = h;
        }
        *(ushort4*)((u16*)(ws + XH_OFF) + idx * 4) = HX.s;
        *(ushort4*)((u16*)(ws + XL_OFF) + idx * 4) = LX.s;
        *(ushort4*)((u16*)(ws + QH_OFF) + idx * 4) = HQ.s;
        *(ushort4*)((u16*)(ws + QL_OFF) + idx * 4) = LQ.s;
    }
}

// MFMA main: staged X -> VGPR, staged W slice -> LDS (coalesced 16B copies),
// a2 folded into the accumulator init (col = r15 -> per-lane constant).
// LDS g-XOR swizzle: logical layout banks on 4*r15 mod 32 only (8-way b128
// conflict); byte ^= g<<5 makes it <=2-way at zero in-loop cost.
__global__ __launch_bounds__(256, 4) void kde_mfma(const unsigned char* __restrict__ ws,
                                                   float* __restrict__ partial) {
    __shared__ u16 LBH[2048], LBL[2048], LCH[2048], LCL[2048];
    __shared__ float A2s[MCH];

    const int t = threadIdx.x;
    const int mb = blockIdx.y;

    // W slice copy: logical byte L = t*16; phys = L ^ (((L>>8)&3)<<5)
    {
        const u32 src = mb * 2048 + t * 8;            // u16 index
        const u32 dst = (t * 16) ^ (((t >> 4) & 3) << 5);  // byte
        *(bf16x8*)((char*)LBH + dst) = *(const bf16x8*)((const u16*)(ws + WBH_OFF) + src);
        *(bf16x8*)((char*)LBL + dst) = *(const bf16x8*)((const u16*)(ws + WBL_OFF) + src);
        *(bf16x8*)((char*)LCH + dst) = *(const bf16x8*)((const u16*)(ws + WCH_OFF) + src);
        *(bf16x8*)((char*)LCL + dst) = *(const bf16x8*)((const u16*)(ws + WCL_OFF) + src);
        if (t < MCH) A2s[t] = ((const float*)(ws + A2_OFF))[mb * MCH + t];
    }

    const int lane = t & 63, wid = t >> 6;
    const int r15 = lane & 15, g = lane >> 4;
    const int n0 = blockIdx.x * 256 + wid * 64;

    bf16x8 xh[4], xl[4], qh[4], ql[4];
#pragma unroll
    for (int nt = 0; nt < 4; ++nt) {
        const size_t off = (size_t)(n0 + nt * 16 + r15) * DD + g * 8;
        xh[nt] = *(const bf16x8*)((const u16*)(ws + XH_OFF) + off);
        xl[nt] = *(const bf16x8*)((const u16*)(ws + XL_OFF) + off);
        qh[nt] = *(const bf16x8*)((const u16*)(ws + QH_OFF) + off);
        ql[nt] = *(const bf16x8*)((const u16*)(ws + QL_OFF) + off);
    }

    __syncthreads();

    f32x4 rs[4];
#pragma unroll
    for (int nt = 0; nt < 4; ++nt) rs[nt] = (f32x4){0.f, 0.f, 0.f, 0.f};

    // per-lane swizzled base (bytes); it-stride 1024B is bank-invariant
    const u32 wbase = ((u32)((g * 16 + r15) * 16)) ^ (g << 5);

#pragma unroll 2
    for (int it = 0; it < NITS; ++it) {
        const u32 b = wbase + it * 1024;
        bf16x8 bh = *(const bf16x8*)((const char*)LBH + b);
        bf16x8 ch = *(const bf16x8*)((const char*)LCH + b);
        bf16x8 bl = *(const bf16x8*)((const char*)LBL + b);
        bf16x8 cl = *(const bf16x8*)((const char*)LCL + b);
        const float a2 = A2s[it * 16 + r15];
#pragma unroll
        for (int nt = 0; nt < 4; ++nt) {
            f32x4 acc = (f32x4){a2, a2, a2, a2};   // col=r15 -> a2 const per lane
            acc = __builtin_amdgcn_mfma_f32_16x16x32_bf16(xh[nt], bh, acc, 0, 0, 0);
            acc = __builtin_amdgcn_mfma_f32_16x16x32_bf16(qh[nt], ch, acc, 0, 0, 0);
            acc = __builtin_amdgcn_mfma_f32_16x16x32_bf16(xl[nt], bh, acc, 0, 0, 0);
            acc = __builtin_amdgcn_mfma_f32_16x16x32_bf16(ql[nt], ch, acc, 0, 0, 0);
            acc = __builtin_amdgcn_mfma_f32_16x16x32_bf16(xh[nt], bl, acc, 0, 0, 0);
            acc = __builtin_amdgcn_mfma_f32_16x16x32_bf16(qh[nt], cl, acc, 0, 0, 0);
#pragma unroll
            for (int r = 0; r < 4; ++r) rs[nt][r] += fast_exp2(acc[r]);
        }
    }

#pragma unroll
    for (int o = 1; o < 16; o <<= 1)
#pragma unroll
        for (int nt = 0; nt < 4; ++nt)
#pragma unroll
            for (int r = 0; r < 4; ++r) rs[nt][r] += __shfl_xor(rs[nt][r], o);

    if (r15 == 0) {
#pragma unroll
        for (int nt = 0; nt < 4; ++nt)
            *(f32x4*)(partial + (size_t)mb * NS + n0 + nt * 16 + g * 4) = rs[nt];
    }
}

// dist[n] = sum_j partial[j][n]; block min/max -> 2 atomics. No last-block tail.
__global__ __launch_bounds__(256) void reduce_mm(const unsigned char* __restrict__ wsb,
                                                 float* __restrict__ dist,
                                                 unsigned* __restrict__ mm) {
    const float* partial = (const float*)(wsb + PART_OFF);
    const int tid = threadIdx.x;
    const int n = blockIdx.x * 256 + tid;
    float v = 0.f;
#pragma unroll
    for (int j = 0; j < MSPLIT; ++j) v += partial[(size_t)j * NS + n];
    dist[n] = v;

    float mn = v, mx = v;
#pragma unroll
    for (int o = 1; o < 64; o <<= 1) {
        mn = fminf(mn, __shfl_xor(mn, o));
        mx = fmaxf(mx, __shfl_xor(mx, o));
    }
    __shared__ float smn[4], smx[4];
    const int wv = tid >> 6, ln = tid & 63;
    if (ln == 0) { smn[wv] = mn; smx[wv] = mx; }
    __syncthreads();
    if (tid == 0) {
#pragma unroll
        for (int j = 1; j < 4; ++j) {
            mn = fminf(mn, smn[j]);
            mx = fmaxf(mx, smx[j]);
        }
        atomicMin(mm + 0, __float_as_uint(mn));
        atomicMax(mm + 1, __float_as_uint(mx));
    }
}

__global__ __launch_bounds__(256) void finalize(const float* __restrict__ dist,
                                                const unsigned* __restrict__ mm,
                                                float* __restrict__ out) {
    const int i = blockIdx.x * 256 + threadIdx.x;   // f32x4 index
    const float fmn = __uint_as_float(mm[0]);
    const float fmx = __uint_as_float(mm[1]);
    f32x4 d = ((const f32x4*)dist)[i];
    f32x4 o;
#pragma unroll
    for (int r = 0; r < 4; ++r) o[r] = fmx + fmn - d[r];
    ((f32x4*)out)[i] = o;
}

extern "C" void kernel_launch(void* const* d_in, const int* in_sizes, int n_in,
                              void* d_out, int out_size, void* d_ws, size_t ws_size,
                              hipStream_t stream) {
    const float* samples = (const float*)d_in[0];
    const float* means   = (const float*)d_in[1];
    const float* stds    = (const float*)d_in[2];
    unsigned char* ws = (unsigned char*)d_ws;
    float* out = (float*)d_out;

    float* dist = (float*)(ws + DIST_OFF);
    unsigned* mm = (unsigned*)(ws + MM_OFF);

    prep<<<dim3(64 + NS * DD / 4 / 256), 256, 0, stream>>>(samples, means, stds, ws);
    kde_mfma<<<dim3(NS / 256, MSPLIT), 256, 0, stream>>>(ws, (float*)(ws + PART_OFF));
    reduce_mm<<<dim3(NS / 256), 256, 0, stream>>>(ws, dist, mm);
    finalize<<<dim3(NS / 4 / 256), 256, 0, stream>>>(dist, mm, out);
}

// Round 16
// 19.186 us; speedup vs baseline: 1.2278x; 1.2278x over previous
//
#include <hip/hip_runtime.h>

#define NS 8192
#define MS 2048
#define DD 32
#define MSPLIT 32
#define MCH 64        // m per block
#define NITS 4        // m-tiles per block
#define RBLK 32       // reduce blocks

typedef __attribute__((ext_vector_type(8))) short bf16x8;
typedef __attribute__((ext_vector_type(4))) float f32x4;
typedef unsigned short u16;
typedef unsigned int u32;

// ws byte offsets
#define PART_OFF 0                          // [MSPLIT][NS] f32 (1 MB)
#define MM_OFF   (MSPLIT * NS * 4)          // 2 u32 (min,max bits)
#define CNT_OFF  (MM_OFF + 8)               // 1 u32

__device__ inline float fast_exp2(float x) {
#if __has_builtin(__builtin_amdgcn_exp2f)
    return __builtin_amdgcn_exp2f(x);
#else
    return exp2f(x);
#endif
}

__device__ inline u32 cvt_pk_bf16(float a, float b) {
    u32 r;
    asm("v_cvt_pk_bf16_f32 %0, %1, %2" : "=v"(r) : "v"(a), "v"(b));
    return r;
}

// Split 8 floats into hi/lo bf16x8 (RNE). Pack-order safe: X and W use the
// same helper, so MFMA dots pair identical k-elements either way.
__device__ inline void split8(const float* v, bf16x8& hi, bf16x8& lo) {
    union { u32 u[4]; bf16x8 b; } H, L;
#pragma unroll
    for (int j = 0; j < 4; ++j) {
        u32 h = cvt_pk_bf16(v[2 * j], v[2 * j + 1]);
        float ha = __uint_as_float(h << 16);
        float hb = __uint_as_float(h & 0xFFFF0000u);
        L.u[j] = cvt_pk_bf16(v[2 * j] - ha, v[2 * j + 1] - hb);
        H.u[j] = h;
    }
    hi = H.b;
    lo = L.b;
}

// R13's proven main (19.5us config) + the a2-in-accumulator init validated in
// R14/R15 (absmax-identical). Also inits mm/cnt for the reduce kernel.
__global__ __launch_bounds__(256, 4) void kde_fused(const float* __restrict__ samples,
                                                    const float* __restrict__ means,
                                                    const float* __restrict__ stds,
                                                    unsigned char* __restrict__ wsb) {
    __shared__ u16 WBH[2048], WBL[2048], WCH[2048], WCL[2048];  // [it][g][r15][8]
    __shared__ float A2s[MCH];

    const int t = threadIdx.x;
    const int m0 = blockIdx.y * MCH;
    const float L2E = 1.4426950408889634f;

    if (blockIdx.x == 0 && blockIdx.y == 0 && t == 0) {
        unsigned* mm = (unsigned*)(wsb + MM_OFF);
        mm[0] = 0x7f7fffffu;  // FLT_MAX bits (uint cmp == float cmp, all positive)
        mm[1] = 0u;
        *(unsigned*)(wsb + CNT_OFF) = 0u;
    }

    // ---- phase 1: W chunk -> LDS, one thread per (m_local, 8-d quarter) ----
    {
        const int ml = t >> 2, qd = t & 3;
        const float* mp = means + (size_t)(m0 + ml) * DD + qd * 8;
        const float* vp = stds  + (size_t)(m0 + ml) * DD + qd * 8;
        float4 a4 = *(const float4*)mp, b4 = *(const float4*)(mp + 4);
        float4 c4 = *(const float4*)vp, d4 = *(const float4*)(vp + 4);
        float mu[8] = {a4.x, a4.y, a4.z, a4.w, b4.x, b4.y, b4.z, b4.w};
        float sd[8] = {c4.x, c4.y, c4.z, c4.w, d4.x, d4.y, d4.z, d4.w};
        float Bv[8], Cv[8], a = 0.f;
#pragma unroll
        for (int j = 0; j < 8; ++j) {
            float inv = 1.0f / sd[j];
            Bv[j] = L2E * mu[j] * inv;
            Cv[j] = -0.5f * L2E * inv;
            a += mu[j] * mu[j] * inv;
        }
        a += __shfl_xor(a, 1);
        a += __shfl_xor(a, 2);
        if (qd == 0) A2s[ml] = -0.5f * L2E * a - 11.0f;  // -log2(M) folds the mean

        bf16x8 bh, bl, ch, cl;
        split8(Bv, bh, bl);
        split8(Cv, ch, cl);
        const int it = ml >> 4, r15 = ml & 15;
        const int base = ((it * 4 + qd) * 16 + r15) * 8;
        *(bf16x8*)&WBH[base] = bh;
        *(bf16x8*)&WBL[base] = bl;
        *(bf16x8*)&WCH[base] = ch;
        *(bf16x8*)&WCL[base] = cl;
    }

    // ---- phase 2: X fragments straight from samples ----
    const int lane = t & 63, wid = t >> 6;
    const int r15 = lane & 15, g = lane >> 4;
    const int n0 = blockIdx.x * 256 + wid * 64;

    bf16x8 xh[4], xl[4], qh[4], ql[4];
#pragma unroll
    for (int nt = 0; nt < 4; ++nt) {
        const float* sp = samples + (size_t)(n0 + nt * 16 + r15) * DD + g * 8;
        float4 a4 = *(const float4*)sp, b4 = *(const float4*)(sp + 4);
        float xv[8] = {a4.x, a4.y, a4.z, a4.w, b4.x, b4.y, b4.z, b4.w};
        float qv[8];
#pragma unroll
        for (int j = 0; j < 8; ++j) qv[j] = xv[j] * xv[j];
        split8(xv, xh[nt], xl[nt]);
        split8(qv, qh[nt], ql[nt]);
    }

    __syncthreads();

    // ---- phase 3: m-loop over LDS-resident W ----
    f32x4 rs[4];
#pragma unroll
    for (int nt = 0; nt < 4; ++nt) rs[nt] = (f32x4){0.f, 0.f, 0.f, 0.f};

#pragma unroll 2
    for (int it = 0; it < NITS; ++it) {
        const int base = ((it * 4 + g) * 16 + r15) * 8;
        bf16x8 bh = *(const bf16x8*)&WBH[base];
        bf16x8 ch = *(const bf16x8*)&WCH[base];
        bf16x8 bl = *(const bf16x8*)&WBL[base];
        bf16x8 cl = *(const bf16x8*)&WCL[base];
        const float a2 = A2s[it * 16 + r15];
#pragma unroll
        for (int nt = 0; nt < 4; ++nt) {
            f32x4 acc = (f32x4){a2, a2, a2, a2};   // col=r15 -> a2 const per lane
            acc = __builtin_amdgcn_mfma_f32_16x16x32_bf16(xh[nt], bh, acc, 0, 0, 0);
            acc = __builtin_amdgcn_mfma_f32_16x16x32_bf16(qh[nt], ch, acc, 0, 0, 0);
            acc = __builtin_amdgcn_mfma_f32_16x16x32_bf16(xl[nt], bh, acc, 0, 0, 0);
            acc = __builtin_amdgcn_mfma_f32_16x16x32_bf16(ql[nt], ch, acc, 0, 0, 0);
            acc = __builtin_amdgcn_mfma_f32_16x16x32_bf16(xh[nt], bl, acc, 0, 0, 0);
            acc = __builtin_amdgcn_mfma_f32_16x16x32_bf16(qh[nt], cl, acc, 0, 0, 0);
#pragma unroll
            for (int r = 0; r < 4; ++r) rs[nt][r] += fast_exp2(acc[r]);
        }
    }

    // sum the 16 m-columns (lanes sharing g)
#pragma unroll
    for (int o = 1; o < 16; o <<= 1)
#pragma unroll
        for (int nt = 0; nt < 4; ++nt)
#pragma unroll
            for (int r = 0; r < 4; ++r) rs[nt][r] += __shfl_xor(rs[nt][r], o);

    float* partial = (float*)(wsb + PART_OFF);
    if (r15 == 0) {
#pragma unroll
        for (int nt = 0; nt < 4; ++nt)
            *(f32x4*)(partial + (size_t)blockIdx.y * NS + n0 + nt * 16 + g * 4) = rs[nt];
    }
}

// Merged reduce+flip: 32 co-resident blocks (<< 256 CUs, no deadlock).
// dist stays in registers; after min/max atomics, a counter rendezvous
// (distributed — NOT R12's single-block serial-volatile tail) lets every
// block flip its own chunk. Saves one graph node + the dist memory round-trip.
__global__ __launch_bounds__(256) void reduce_flip(unsigned char* __restrict__ wsb,
                                                   float* __restrict__ out) {
    const float* partial = (const float*)(wsb + PART_OFF);
    unsigned* mm = (unsigned*)(wsb + MM_OFF);
    unsigned* cnt = (unsigned*)(wsb + CNT_OFF);

    const int tid = threadIdx.x;
    const int n = blockIdx.x * 256 + tid;
    float v = 0.f;
#pragma unroll
    for (int j = 0; j < MSPLIT; ++j) v += partial[(size_t)j * NS + n];

    float mn = v, mx = v;
#pragma unroll
    for (int o = 1; o < 64; o <<= 1) {
        mn = fminf(mn, __shfl_xor(mn, o));
        mx = fmaxf(mx, __shfl_xor(mx, o));
    }
    __shared__ float smn[4], smx[4];
    __shared__ float sres[2];
    const int wv = tid >> 6, ln = tid & 63;
    if (ln == 0) { smn[wv] = mn; smx[wv] = mx; }
    __syncthreads();
    if (tid == 0) {
#pragma unroll
        for (int j = 1; j < 4; ++j) {
            mn = fminf(mn, smn[j]);
            mx = fmaxf(mx, smx[j]);
        }
        atomicMin(mm + 0, __float_as_uint(mn));
        atomicMax(mm + 1, __float_as_uint(mx));
        __threadfence();                       // release our atomics
        atomicAdd(cnt, 1u);
        // spin until all RBLK blocks have contributed (all co-resident)
        while (__hip_atomic_load(cnt, __ATOMIC_ACQUIRE, __HIP_MEMORY_SCOPE_AGENT)
               < RBLK) {}
        sres[0] = __uint_as_float(
            __hip_atomic_load(mm + 0, __ATOMIC_RELAXED, __HIP_MEMORY_SCOPE_AGENT));
        sres[1] = __uint_as_float(
            __hip_atomic_load(mm + 1, __ATOMIC_RELAXED, __HIP_MEMORY_SCOPE_AGENT));
    }
    __syncthreads();
    out[n] = sres[1] + sres[0] - v;
}

extern "C" void kernel_launch(void* const* d_in, const int* in_sizes, int n_in,
                              void* d_out, int out_size, void* d_ws, size_t ws_size,
                              hipStream_t stream) {
    const float* samples = (const float*)d_in[0];
    const float* means   = (const float*)d_in[1];
    const float* stds    = (const float*)d_in[2];
    unsigned char* ws = (unsigned char*)d_ws;
    float* out = (float*)d_out;

    kde_fused<<<dim3(NS / 256, MSPLIT), 256, 0, stream>>>(samples, means, stds, ws);
    reduce_flip<<<dim3(RBLK), 256, 0, stream>>>(ws, out);
}